// Round 24
// baseline (73.006 us; speedup 1.0000x reference)
//
#include <hip/hip_runtime.h>
#include <math.h>

#define BB  64
#define WW  128
#define NN  64
#define HIDN 77

// ================= K1: fused front v4: 512 blk x 512 thr, 8 rows/blk, 78.8 KB (2 blk/CU) =================
// LDS floats (19696 total):
//   [0,17920)      Ws [140][128]; rows 75..139 staged late; XT [64][129] borrows [9600,17856) in P0-P3;
//                  W1 [128][78] then W2 [77][128] overlay base after P4.
//   [17920,19072)  XA 8x144 (recT [128][9] overlays after P6)
//   [19072,19696)  Sm 8x68 + cnt(int 64)  -> hm [8][78] overlays after P3
__global__ __launch_bounds__(512) void k_front(
    const float* __restrict__ x, const float* __restrict__ emb,
    const float* __restrict__ wg, const float* __restrict__ gcn_b,
    const float* __restrict__ w1, const float* __restrict__ b1,
    const float* __restrict__ w2, const float* __restrict__ b2,
    const int* __restrict__ gl_ei, int E_gl,
    const int* __restrict__ gat_ei, int E_gat,
    const float* __restrict__ gat_w, const float* __restrict__ asrc,
    const float* __restrict__ adst, const float* __restrict__ fcw,
    const float* __restrict__ gat_b,
    float* __restrict__ xs, float* __restrict__ out_rec,
    float* __restrict__ VAV, int* __restrict__ gat_off, int* __restrict__ gat_list) {
  __shared__ float smem[19696];   // 78784 B
  float* Ws   = smem;             // [140][128]
  float* XT   = smem + 9600;      // [64][129] (borrowed tail of Ws)
  float* XA   = smem + 17920;     // 8x144
  float* recT = smem + 17920;     // [128][9] overlays XA
  float* Sm   = smem + 19072;     // 8x68
  int*   cnt  = (int*)(smem + 19616);  // 64
  float* hm   = smem + 19072;     // [8][78] overlays Sm+cnt

  int tid = threadIdx.x;

  // ---- spare blocks: 512..514 = VAV matvecs; 515 = GAT CSR ----
  if (blockIdx.x >= 512) {
    int which = blockIdx.x - 512;
    if (which < 3) {
      const float* vecg = (which == 0) ? asrc : (which == 1) ? adst : fcw;
      if (tid < 128) {
        float acc = 0.f;
#pragma unroll 4
        for (int k = 0; k < 128; k++) acc += gat_w[tid * 128 + k] * vecg[k];
        VAV[which * 128 + tid] = acc;
      }
      if (which == 2) {
        float* red = smem;
        if (tid < 128) red[tid] = gat_b[tid] * fcw[tid];
        __syncthreads();
        if (tid == 0) {
          float s = 0.f;
          for (int i = 0; i < 128; i++) s += red[i];
          VAV[384] = s;
        }
      }
    } else {
      int* ip   = (int*)smem;
      int* offs = ip;
      int* cur  = ip + 65;
      int* cntg = ip + 129;
      int* lst  = ip + 193;
      if (tid < 64) cntg[tid] = 1;
      __syncthreads();
      for (int e = tid; e < E_gat; e += 512) atomicAdd(&cntg[gat_ei[BB * E_gat + e]], 1);
      __syncthreads();
      if (tid == 0) { int s = 0; for (int n = 0; n < 64; n++) { offs[n] = s; s += cntg[n]; } offs[64] = s; }
      __syncthreads();
      if (tid < 64) cur[tid] = offs[tid];
      __syncthreads();
      for (int e = tid; e < E_gat; e += 512) {
        int src = gat_ei[e], dst = gat_ei[BB * E_gat + e];
        lst[atomicAdd(&cur[dst], 1)] = src;
      }
      if (tid < 64) lst[atomicAdd(&cur[tid], 1)] = tid;
      __syncthreads();
      if (tid < 65) gat_off[tid] = offs[tid];
      int tot = offs[64];
      for (int t = tid; t < tot; t += 512) gat_list[t] = lst[t];
    }
    return;
  }

  int r0 = blockIdx.x * 8;
  int b = r0 >> 6, n0 = r0 & 63;
  const float* xb = x + (size_t)b * 8192;

  // P0: stage Ws rows 0..74 (coalesced) + XT (coalesced global, conflict-free LDS); init Sm, cnt
  {
    const float4* W4 = (const float4*)wg;
    float4* Ws4 = (float4*)Ws;
    for (int t = tid; t < 2400; t += 512) Ws4[t] = W4[t];
  }
  for (int t = tid; t < 8192; t += 512)
    XT[(t & 63) * 129 + (t >> 6)] = xb[t];
  for (int t = tid; t < 544; t += 512) Sm[t] = 0.f;
  if (tid < 64) cnt[tid] = 1;  // self-loop
  __syncthreads();

  // P1: edge scan: degree + indicator (owned rows n0..n0+7)
  for (int e = tid; e < E_gl; e += 512) {
    int dst = gl_ei[BB * E_gl + e];
    atomicAdd(&cnt[dst], 1);
    int d = dst - n0;
    if ((unsigned)d < 8u) Sm[d * 68 + gl_ei[e]] = 1.0f;
  }
  __syncthreads();

  // P2: scale indicators -> coefs + self-loop
  for (int t = tid; t < 544; t += 512) {
    int i = t / 68, s = t % 68;
    if (s < 64) {
      float di = rsqrtf((float)cnt[n0 + i]);
      float v = Sm[t] * rsqrtf((float)cnt[s]) * di;
      if (s == n0 + i) v += di * di;
      Sm[t] = v;
    }
  }
  __syncthreads();

  // P3: XA[i][w] = sum_s Sm[i][s]*XT[s][w]  (thread = row i x 2 w's; stride-1 lanes)
  {
    int i = tid >> 6, tw = tid & 63;
    const float* Sr = Sm + i * 68;
    float o0 = 0, o1 = 0;
#pragma unroll 4
    for (int s = 0; s < 64; s++) {
      float sv = Sr[s];
      o0 += sv * XT[s * 129 + tw];
      o1 += sv * XT[s * 129 + tw + 64];
    }
    XA[i * 144 + tw] = o0;
    XA[i * 144 + tw + 64] = o1;
  }
  if (tid < 96) {
    int i = tid / 12, j = tid % 12;
    const float* Sr = Sm + i * 68;
    float a = 0.f;
    for (int s = 0; s < 64; s++) a += Sr[s] * emb[s * 12 + j];
    XA[i * 144 + 128 + j] = a;
  }
  __syncthreads();

  // P3b: stage Ws rows 75..139 over dead XT (uniform k*128 indexing preserved: 75*128 == 9600)
  {
    const float4* W4 = (const float4*)wg;
    float4* Ws4 = (float4*)Ws;
    for (int t = tid; t < 2080; t += 512) Ws4[2400 + t] = W4[2400 + t];
  }
  __syncthreads();

  // P4: GEMM1 (8x140 @ 140x128), 1r x 2c, full K; then W1 [128][78] stage at base
  {
    int row = tid >> 6, cg = tid & 63;
    int c0 = cg * 2;
    float a0 = 0, a1 = 0;
    const float* Ar = XA + row * 144;
#pragma unroll 4
    for (int k = 0; k < 140; k++) {
      float2 wv = *(const float2*)&Ws[k * 128 + c0];
      float a = Ar[k];
      a0 += a * wv.x; a1 += a * wv.y;
    }
    __syncthreads();   // all Ws/XA reads done
    XA[row * 144 + c0]     = fmaxf(a0 + gcn_b[c0], 0.f);
    XA[row * 144 + c0 + 1] = fmaxf(a1 + gcn_b[c0 + 1], 0.f);
    for (int q = tid; q < 9984; q += 512) {
      int k = q / 78, c = q % 78;
      Ws[q] = (c < HIDN) ? w1[k * HIDN + c] : 0.f;
    }
  }
  __syncthreads();

  // P6: hm = tanh(XA @ W1 + b1), 312 active (8 rows x 39 col-pairs), K=128
  {
    if (tid < 312) {
      int rp = tid / 39, cg = tid % 39;
      int c0 = cg * 2;
      float a0 = 0, a1 = 0;
      const float* Ar = XA + rp * 144;
#pragma unroll 4
      for (int k = 0; k < 128; k++) {
        float2 wv = *(const float2*)&Ws[k * 78 + c0];
        float a = Ar[k];
        a0 += a * wv.x; a1 += a * wv.y;
      }
      float b0v = (c0 < HIDN) ? b1[c0] : 0.f;
      float b1v = (c0 + 1 < HIDN) ? b1[c0 + 1] : 0.f;
      hm[rp * 78 + c0]     = tanhf(a0 + b0v);
      hm[rp * 78 + c0 + 1] = tanhf(a1 + b1v);
    }
  }
  __syncthreads();
  // P7: stage W2 [77][128] at base
  {
    const float4* w24 = (const float4*)w2;
    float4* Wb4 = (float4*)smem;
    for (int t = tid; t < 2464; t += 512) Wb4[t] = w24[t];
  }
  __syncthreads();

  // P8: x_rec = tanh(hm @ W2 + b2); xs = x + x_rec (x direct, L1-hot); recT over dead XA
  {
    int row = tid >> 6, cg = tid & 63;
    int c0 = cg * 2;
    float a0 = 0, a1 = 0;
    const float* Hr = hm + row * 78;
#pragma unroll 4
    for (int k = 0; k < HIDN; k++) {
      float2 wv = *(const float2*)&smem[k * 128 + c0];
      float a = Hr[k];
      a0 += a * wv.x; a1 += a * wv.y;
    }
    float x0 = tanhf(a0 + b2[c0]);
    float x1 = tanhf(a1 + b2[c0 + 1]);
    int nn = n0 + row;
    float s0 = x0 + xb[c0 * 64 + nn];
    float s1 = x1 + xb[(c0 + 1) * 64 + nn];
    *(float2*)&xs[(size_t)(r0 + row) * 128 + c0] = make_float2(s0, s1);
    recT[c0 * 9 + row] = x0;
    recT[(c0 + 1) * 9 + row] = x1;
  }
  __syncthreads();
  // P9: out_rec (coalesced)
  float* orc = out_rec + (size_t)b * 8192 + n0;
  for (int t = tid; t < 1024; t += 512) {
    int w = t >> 3, i = t & 7;
    orc[w * 64 + i] = recT[w * 9 + i];
  }
}

// ================= K2: attn with LDS-GEMM L/R projection + fused rank-1 GAT dots (R21-proven) =================
__global__ __launch_bounds__(512) void k_attn(const float* __restrict__ xs, const float* __restrict__ ta_w,
                                              const float* __restrict__ ta_b, const float* __restrict__ ta_a,
                                              const float* __restrict__ ta_bias, const float* __restrict__ VAV,
                                              float* __restrict__ PART) {
  __shared__ float smem[38272];   // 153088 B
  float* Rf  = smem;
  float* XN  = smem + 16384;      // [64][136]
  float* WT  = smem + 25088;      // [128][65]
  float* Lh  = smem + 33408;
  float* av2 = smem + 37632;
  float* av6 = smem + 37760;
  float* tbs = smem + 37888;
  float* uu  = smem + 38016;
  float* vv  = smem + 38048;
  float* vva = smem + 38176;
  float* vvd = smem + 38208;
  float* vvf = smem + 38240;
  float* scratch = WT;

  int tid = threadIdx.x;
  int b = blockIdx.x >> 2, q = blockIdx.x & 3;
  int i0 = q * 32;

  {
    const float* xsb = xs + (size_t)b * 8192;
#pragma unroll
    for (int t = 0; t < 16; t++) {
      int idx = tid + t * 512;
      XN[(idx >> 7) * 136 + (idx & 127)] = xsb[idx];
    }
  }
#pragma unroll
  for (int t = 0; t < 16; t++) {
    int idx = tid + t * 512;
    int e = idx & 127, n = idx >> 7;
    WT[e * 65 + n] = ta_w[(64 + n) * 128 + e];
  }
  if (tid < 128) {
    float a = ta_a[tid];
    av2[tid] = 0.4f * a; av6[tid] = 0.6f * a;
    tbs[tid] = ta_b[tid];
  }
  if (tid >= 128 && tid < 160) {
    int i = tid - 128;
    vva[i] = VAV[i0 + i];
    vvd[i] = VAV[128 + i0 + i];
    vvf[i] = VAV[256 + i0 + i];
  }
  __syncthreads();

  {
    int et = tid >> 4, jt = tid & 15;
    int e0 = et * 4, j0 = jt * 8;
    float acc[4][8];
#pragma unroll
    for (int r = 0; r < 4; r++)
#pragma unroll
      for (int c = 0; c < 8; c++) acc[r][c] = 0.f;
#pragma unroll 4
    for (int n = 0; n < 64; n++) {
      float4 b0 = *(const float4*)&XN[n * 136 + j0];
      float4 b1 = *(const float4*)&XN[n * 136 + j0 + 4];
      float bb[8] = {b0.x, b0.y, b0.z, b0.w, b1.x, b1.y, b1.z, b1.w};
#pragma unroll
      for (int r = 0; r < 4; r++) {
        float a = WT[(e0 + r) * 65 + n];
#pragma unroll
        for (int c = 0; c < 8; c++) acc[r][c] += a * bb[c];
      }
    }
#pragma unroll
    for (int r = 0; r < 4; r++) {
      *(float4*)&Rf[(e0 + r) * 128 + j0] = make_float4(acc[r][0], acc[r][1], acc[r][2], acc[r][3]);
      *(float4*)&Rf[(e0 + r) * 128 + j0 + 4] = make_float4(acc[r][4], acc[r][5], acc[r][6], acc[r][7]);
    }
  }
  __syncthreads();
#pragma unroll
  for (int t = 0; t < 16; t++) {
    int idx = tid + t * 512;
    int e = idx & 127, n = idx >> 7;
    WT[e * 65 + n] = ta_w[n * 128 + e];
  }
  __syncthreads();

  {
    int e = tid >> 2, ig = tid & 3;
    int ii = ig * 8;
    float acc[8];
#pragma unroll
    for (int c = 0; c < 8; c++) acc[c] = 0.f;
#pragma unroll 4
    for (int n = 0; n < 64; n++) {
      float4 b0 = *(const float4*)&XN[n * 136 + i0 + ii];
      float4 b1 = *(const float4*)&XN[n * 136 + i0 + ii + 4];
      float a = WT[e * 65 + n];
      acc[0] += a * b0.x; acc[1] += a * b0.y; acc[2] += a * b0.z; acc[3] += a * b0.w;
      acc[4] += a * b1.x; acc[5] += a * b1.y; acc[6] += a * b1.z; acc[7] += a * b1.w;
    }
    float tb = tbs[e];
#pragma unroll
    for (int c = 0; c < 8; c++) Lh[e * 32 + ii + c] = acc[c] + tb;
  }
  __syncthreads();

  if (tid < 160) {
    float acc = 0.f;
    if (tid < 128) {
      for (int e = 0; e < 128; e++) acc += av6[e] * Rf[e * 128 + tid];
      vv[tid] = acc;
    } else {
      int i = tid - 128;
      for (int e = 0; e < 128; e++) acc += av6[e] * Lh[e * 32 + i];
      uu[i] = acc;
    }
  }
  __syncthreads();

  bool act = tid < 256;
  int tj = tid & 31, ti = (tid >> 5) & 7;
  float p[4][4];
  if (act) {
    float acc[4][4];
#pragma unroll
    for (int a = 0; a < 4; a++)
#pragma unroll
      for (int j = 0; j < 4; j++) acc[a][j] = 0.f;
#pragma unroll 2
    for (int e = 0; e < 128; e++) {
      float4 Lv = *(const float4*)&Lh[e * 32 + ti * 4];
      float4 Rv = *(const float4*)&Rf[e * 128 + tj * 4];
      float ae = av2[e];
      float La[4] = {Lv.x, Lv.y, Lv.z, Lv.w};
      float Ra[4] = {Rv.x, Rv.y, Rv.z, Rv.w};
#pragma unroll
      for (int a = 0; a < 4; a++)
#pragma unroll
        for (int j = 0; j < 4; j++) {
          float t = La[a] + Ra[j];
          acc[a][j] += ae * fabsf(t);
        }
    }
#pragma unroll
    for (int a = 0; a < 4; a++) {
      int i = i0 + ti * 4 + a;
      float uvi = uu[ti * 4 + a];
      float4 bv = *(const float4*)&ta_bias[(size_t)i * 128 + tj * 4];
      float v0 = acc[a][0] + bv.x + uvi + vv[tj * 4 + 0];
      float v1 = acc[a][1] + bv.y + uvi + vv[tj * 4 + 1];
      float v2 = acc[a][2] + bv.z + uvi + vv[tj * 4 + 2];
      float v3 = acc[a][3] + bv.w + uvi + vv[tj * 4 + 3];
      float m = fmaxf(fmaxf(v0, v1), fmaxf(v2, v3));
#pragma unroll
      for (int o = 16; o > 0; o >>= 1) m = fmaxf(m, __shfl_xor(m, o));
      float e0 = __expf(v0 - m), e1 = __expf(v1 - m), e2 = __expf(v2 - m), e3 = __expf(v3 - m);
      float s = e0 + e1 + e2 + e3;
#pragma unroll
      for (int o = 16; o > 0; o >>= 1) s += __shfl_xor(s, o);
      float inv = 1.f / s;
      p[a][0] = e0 * inv; p[a][1] = e1 * inv; p[a][2] = e2 * inv; p[a][3] = e3 * inv;
    }
  }
  __syncthreads();
  float* P = Lh;
  if (act) {
#pragma unroll
    for (int a = 0; a < 4; a++)
      *(float4*)&P[(ti * 4 + a) * 132 + tj * 4] = make_float4(p[a][0], p[a][1], p[a][2], p[a][3]);
  }
  __syncthreads();

  int tn = tid & 15, i2 = tid >> 4;
  float o0 = 0, o1 = 0, o2 = 0, o3 = 0;
  const float* Prow = P + i2 * 132;
  const float* X0 = XN + (tn +  0) * 136;
  const float* X1 = XN + (tn + 16) * 136;
  const float* X2 = XN + (tn + 32) * 136;
  const float* X3 = XN + (tn + 48) * 136;
#pragma unroll 4
  for (int j4 = 0; j4 < 32; j4++) {
    float4 pv = *(const float4*)&Prow[j4 * 4];
    float4 a0 = *(const float4*)&X0[j4 * 4];
    float4 a1 = *(const float4*)&X1[j4 * 4];
    float4 a2 = *(const float4*)&X2[j4 * 4];
    float4 a3 = *(const float4*)&X3[j4 * 4];
    o0 += pv.x * a0.x + pv.y * a0.y + pv.z * a0.z + pv.w * a0.w;
    o1 += pv.x * a1.x + pv.y * a1.y + pv.z * a1.z + pv.w * a1.w;
    o2 += pv.x * a2.x + pv.y * a2.y + pv.z * a2.z + pv.w * a2.w;
    o3 += pv.x * a3.x + pv.y * a3.y + pv.z * a3.z + pv.w * a3.w;
  }
  float t0 = tanhf(o0), t1 = tanhf(o1), t2 = tanhf(o2), t3 = tanhf(o3);
  {
    float wa = vva[i2], wd = vvd[i2], wf = vvf[i2];
    int base = i2 * 66 + tn;
    scratch[base +  0] = t0 * wa; scratch[base + 16] = t1 * wa;
    scratch[base + 32] = t2 * wa; scratch[base + 48] = t3 * wa;
    scratch[2112 + base +  0] = t0 * wd; scratch[2112 + base + 16] = t1 * wd;
    scratch[2112 + base + 32] = t2 * wd; scratch[2112 + base + 48] = t3 * wd;
    scratch[4224 + base +  0] = t0 * wf; scratch[4224 + base + 16] = t1 * wf;
    scratch[4224 + base + 32] = t2 * wf; scratch[4224 + base + 48] = t3 * wf;
  }
  __syncthreads();
  if (tid < 192) {
    int arr = tid >> 6, n = tid & 63;
    const float* sp = scratch + arr * 2112 + n;
    float s = 0.f;
#pragma unroll 8
    for (int i = 0; i < 32; i++) s += sp[i * 66];
    PART[(size_t)b * 768 + q * 192 + arr * 64 + n] = s;
  }
}

// ================= K3: final edge-softmax + FC (tiny) =================
__global__ __launch_bounds__(64) void k_fin(const float* __restrict__ PART, const float* __restrict__ VAV,
                                            const int* __restrict__ off, const int* __restrict__ list,
                                            const float* __restrict__ fcb, float* __restrict__ outp) {
  __shared__ float ss_s[64], sd_s[64], pf_s[64];
  int tid = threadIdx.x, b = blockIdx.x;
  const float* pb = PART + (size_t)b * 768;
  {
    float s0 = 0, s1 = 0, s2 = 0;
#pragma unroll
    for (int q2 = 0; q2 < 4; q2++) {
      const float* p = pb + q2 * 192;
      s0 += p[tid]; s1 += p[64 + tid]; s2 += p[128 + tid];
    }
    ss_s[tid] = s0; sd_s[tid] = s1; pf_s[tid] = s2;
  }
  __syncthreads();
  int e0 = off[tid], e1 = off[tid + 1];
  float sdv = sd_s[tid];
  float mx = -1e30f;
  for (int e = e0; e < e1; e++) {
    float t = ss_s[list[e]] + sdv;
    t = fmaxf(t, 0.2f * t);
    mx = fmaxf(mx, t);
  }
  float den = 0.f, acc = 0.f;
  for (int e = e0; e < e1; e++) {
    int s = list[e];
    float t = ss_s[s] + sdv;
    t = fmaxf(t, 0.2f * t);
    float w = __expf(t - mx);
    den += w;
    acc += w * pf_s[s];
  }
  outp[b * 64 + tid] = tanhf(acc / den + VAV[384] + fcb[0]);
}

extern "C" void kernel_launch(void* const* d_in, const int* in_sizes, int n_in,
                              void* d_out, int out_size, void* d_ws, size_t ws_size,
                              hipStream_t stream) {
  (void)n_in; (void)out_size; (void)ws_size;
  const float* x        = (const float*)d_in[0];
  const float* gl_embed = (const float*)d_in[7];
  const float* gcn_w    = (const float*)d_in[8];
  const float* gcn_b    = (const float*)d_in[9];
  const float* mlp_w1   = (const float*)d_in[10];
  const float* mlp_b1   = (const float*)d_in[11];
  const float* mlp_w2   = (const float*)d_in[12];
  const float* mlp_b2   = (const float*)d_in[13];
  const float* ta_w     = (const float*)d_in[14];
  const float* ta_b     = (const float*)d_in[15];
  const float* ta_a     = (const float*)d_in[16];
  const float* ta_bias  = (const float*)d_in[17];
  const float* gat_w    = (const float*)d_in[18];
  const float* gat_asrc = (const float*)d_in[19];
  const float* gat_adst = (const float*)d_in[20];
  const float* gat_b    = (const float*)d_in[21];
  const float* fc_w     = (const float*)d_in[22];
  const float* fc_b     = (const float*)d_in[23];
  const int*   gat_ei   = (const int*)d_in[24];
  const int*   gl_ei    = (const int*)d_in[25];

  int E_gat = in_sizes[24] / (2 * BB);  // 1280
  int E_gl  = in_sizes[25] / (2 * BB);  // 1638

  float* ws = (float*)d_ws;
  float* XS    = ws + 0;        // 524288
  int*   IP    = (int*)(ws + 524288);
  int* GATOFF  = IP;            // 72
  int* GATLIST = IP + 72;       // 2048
  float* VAV   = ws + 526848;   // 512
  float* PART  = ws + 527360;   // 49152

  float* out_rec = (float*)d_out;
  float* out_pre = (float*)d_out + 524288;

  k_front<<<516, 512, 0, stream>>>(x, gl_embed, gcn_w, gcn_b, mlp_w1, mlp_b1, mlp_w2, mlp_b2,
                                   gl_ei, E_gl, gat_ei, E_gat,
                                   gat_w, gat_asrc, gat_adst, fc_w, gat_b,
                                   XS, out_rec, VAV, GATOFF, GATLIST);
  k_attn<<<256, 512, 0, stream>>>(XS, ta_w, ta_b, ta_a, ta_bias, VAV, PART);
  k_fin<<<64, 64, 0, stream>>>(PART, VAV, GATOFF, GATLIST, fc_b, out_pre);
}

// Round 25
// 67.302 us; speedup vs baseline: 1.0847x; 1.0847x over previous
//
#include <hip/hip_runtime.h>
#include <math.h>

#define BB  64
#define WW  128
#define NN  64
#define HIDN 77

// ================= K1: fused front v3 (R21-proven): 1024 thr, coalesced x staging =================
__global__ __launch_bounds__(1024) void k_front(
    const float* __restrict__ x, const float* __restrict__ emb,
    const float* __restrict__ wg, const float* __restrict__ gcn_b,
    const float* __restrict__ w1, const float* __restrict__ b1,
    const float* __restrict__ w2, const float* __restrict__ b2,
    const int* __restrict__ gl_ei, int E_gl,
    const int* __restrict__ gat_ei, int E_gat,
    const float* __restrict__ gat_w, const float* __restrict__ asrc,
    const float* __restrict__ adst, const float* __restrict__ fcw,
    const float* __restrict__ gat_b,
    float* __restrict__ xs, float* __restrict__ out_rec,
    float* __restrict__ VAV, int* __restrict__ gat_off, int* __restrict__ gat_list) {
  __shared__ float smem[37312];   // 149248 B
  float* Ws   = smem;
  float* W1s  = smem + 17920;
  float* XT   = smem + 17920;     // [64][132] overlays W1s region
  float* XA   = smem + 28160;
  float* Sm   = smem + 30464;
  float* xbt  = smem + 31552;
  float* hm   = smem + 33664;
  float* recT = smem + 34944;
  float* gbb  = smem + 37120;
  int*   cnt  = (int*)(smem + 37248);
  float* scr4 = smem + 33664;
  float* scr6 = smem + 34944;

  int tid = threadIdx.x;

  // ---- spare blocks: 256..258 = VAV matvecs; 259 = GAT CSR ----
  if (blockIdx.x >= 256) {
    int which = blockIdx.x - 256;
    if (which < 3) {
      const float* vecg = (which == 0) ? asrc : (which == 1) ? adst : fcw;
      if (tid < 128) {
        float acc = 0.f;
#pragma unroll 4
        for (int k = 0; k < 128; k++) acc += gat_w[tid * 128 + k] * vecg[k];
        VAV[which * 128 + tid] = acc;
      }
      if (which == 2) {
        float* red = smem;
        if (tid < 128) red[tid] = gat_b[tid] * fcw[tid];
        __syncthreads();
        if (tid == 0) {
          float s = 0.f;
          for (int i = 0; i < 128; i++) s += red[i];
          VAV[384] = s;
        }
      }
    } else {
      int* ip   = (int*)smem;
      int* offs = ip;
      int* cur  = ip + 65;
      int* cntg = ip + 129;
      int* lst  = ip + 193;
      if (tid < 64) cntg[tid] = 1;
      __syncthreads();
      for (int e = tid; e < E_gat; e += 1024) atomicAdd(&cntg[gat_ei[BB * E_gat + e]], 1);
      __syncthreads();
      if (tid == 0) { int s = 0; for (int n = 0; n < 64; n++) { offs[n] = s; s += cntg[n]; } offs[64] = s; }
      __syncthreads();
      if (tid < 64) cur[tid] = offs[tid];
      __syncthreads();
      for (int e = tid; e < E_gat; e += 1024) {
        int src = gat_ei[e], dst = gat_ei[BB * E_gat + e];
        lst[atomicAdd(&cur[dst], 1)] = src;
      }
      if (tid < 64) lst[atomicAdd(&cur[tid], 1)] = tid;
      __syncthreads();
      if (tid < 65) gat_off[tid] = offs[tid];
      int tot = offs[64];
      for (int t = tid; t < tot; t += 1024) gat_list[t] = lst[t];
    }
    return;
  }

  int r0 = blockIdx.x * 16;
  int b = r0 >> 6, n0 = r0 & 63;
  const float* xb = x + (size_t)b * 8192;

  // P0: stage Ws (coalesced) + XT = x[b]^T (coalesced global reads); init Sm, gbb, cnt
  {
    const float4* W4 = (const float4*)wg;
    float4* Ws4 = (float4*)Ws;
    for (int t = tid; t < 4480; t += 1024) Ws4[t] = W4[t];
  }
  for (int t = tid; t < 8192; t += 1024)
    XT[(t & 63) * 132 + (t >> 6)] = xb[t];     // linear global read; LDS scatter
  for (int t = tid; t < 1088; t += 1024) Sm[t] = 0.f;
  if (tid < 128) gbb[tid] = gcn_b[tid];
  if (tid < 64) cnt[tid] = 1;  // self-loop
  __syncthreads();

  // P1: edge scan + xbt copy from XT
  for (int e = tid; e < E_gl; e += 1024) {
    int dst = gl_ei[BB * E_gl + e];
    atomicAdd(&cnt[dst], 1);
    int d = dst - n0;
    if ((unsigned)d < 16u) Sm[d * 68 + gl_ei[e]] = 1.0f;
  }
  for (int t = tid; t < 2048; t += 1024) {
    int i = t >> 7, w = t & 127;
    xbt[i * 132 + w] = XT[(n0 + i) * 132 + w];
  }
  __syncthreads();

  // P2: scale indicators -> coefs + self-loop
  for (int t = tid; t < 1088; t += 1024) {
    int i = t / 68, s = t % 68;
    if (s < 64) {
      float di = rsqrtf((float)cnt[n0 + i]);
      float v = Sm[t] * rsqrtf((float)cnt[s]) * di;
      if (s == n0 + i) v += di * di;
      Sm[t] = v;
    }
  }
  __syncthreads();

  // P3: XA[i][w] = sum_s Sm[i][s]*XT[s][w]
  {
    int i = tid >> 6, tw = tid & 63;
    const float* Sr = Sm + i * 68;
    float o0 = 0, o1 = 0;
#pragma unroll 4
    for (int s = 0; s < 64; s++) {
      float sv = Sr[s];
      o0 += sv * XT[s * 132 + tw];
      o1 += sv * XT[s * 132 + tw + 64];
    }
    float* Xr = XA + i * 144;
    Xr[tw] = o0; Xr[tw + 64] = o1;
  }
  if (tid < 192) {
    int i = tid / 12, j = tid % 12;
    const float* Sr = Sm + i * 68;
    float a = 0.f;
    for (int s = 0; s < 64; s++) a += Sr[s] * emb[s * 12 + j];
    XA[i * 144 + 128 + j] = a;
  }
  __syncthreads();

  // P4: GEMM1 (16x140 @ 140x128), 1r x 4c x k-split-2; then W1 stage over dead XT region
  {
    int half = tid >> 9, t = tid & 511;
    int row = t >> 5, cg = t & 31;
    int c0 = cg * 4;
    float a0 = 0, a1 = 0, a2 = 0, a3 = 0;
    const float* Ar = XA + row * 144;
    int k0 = half * 70;
#pragma unroll 5
    for (int k = k0; k < k0 + 70; k++) {
      float4 wv = *(const float4*)&Ws[k * 128 + c0];
      float a = Ar[k];
      a0 += a * wv.x; a1 += a * wv.y; a2 += a * wv.z; a3 += a * wv.w;
    }
    if (half) *(float4*)&scr4[t * 4] = make_float4(a0, a1, a2, a3);
    __syncthreads();
    if (!half) {
      float4 p = *(const float4*)&scr4[t * 4];
      float4 bv = *(const float4*)&gbb[c0];
      *(float4*)&XA[row * 144 + c0] = make_float4(
          fmaxf(a0 + p.x + bv.x, 0.f), fmaxf(a1 + p.y + bv.y, 0.f),
          fmaxf(a2 + p.z + bv.z, 0.f), fmaxf(a3 + p.w + bv.w, 0.f));
    }
    for (int q = tid; q < 10240; q += 1024) {
      int k = q / 80, c = q % 80;
      W1s[q] = (c < HIDN) ? w1[k * HIDN + c] : 0.f;
    }
  }
  __syncthreads();

  // P6: hm = tanh(hA @ W1 + b1), 1r x 4c x k-split-2, 640 active
  {
    bool act = tid < 640;
    int half6 = (tid >= 320) ? 1 : 0;
    int s = act ? (half6 ? tid - 320 : tid) : 0;
    int rp = s / 20, cg = s % 20;
    int c0 = cg * 4;
    float a0 = 0, a1 = 0, a2 = 0, a3 = 0;
    if (act) {
      const float* Ar = XA + rp * 144;
      int k0 = half6 * 64;
#pragma unroll 4
      for (int k = k0; k < k0 + 64; k++) {
        float4 wv = *(const float4*)&W1s[k * 80 + c0];
        float a = Ar[k];
        a0 += a * wv.x; a1 += a * wv.y; a2 += a * wv.z; a3 += a * wv.w;
      }
      if (half6) *(float4*)&scr6[s * 4] = make_float4(a0, a1, a2, a3);
    }
    __syncthreads();
    if (act && !half6) {
      float4 p = *(const float4*)&scr6[s * 4];
      float rv[4] = {a0 + p.x, a1 + p.y, a2 + p.z, a3 + p.w};
#pragma unroll
      for (int j = 0; j < 4; j++) {
        int c = c0 + j;
        float bb = (c < HIDN) ? b1[c] : 0.f;
        hm[rp * 80 + c] = tanhf(rv[j] + bb);
      }
    }
  }
  __syncthreads();
  // P7: stage W2 @ Ws base
  {
    const float4* w24 = (const float4*)w2;
    float4* Wb4 = (float4*)smem;
    for (int t = tid; t < 2464; t += 1024) Wb4[t] = w24[t];
  }
  __syncthreads();

  // P8: x_rec = tanh(hm @ W2 + b2); xs = xbt + x_rec; recT (512 active)
  {
    if (tid < 512) {
      int row = tid >> 5, cg = tid & 31;
      int c0 = cg * 4;
      float a0 = 0, a1 = 0, a2 = 0, a3 = 0;
      const float* Hr = hm + row * 80;
#pragma unroll 4
      for (int k = 0; k < HIDN; k++) {
        float4 wv = *(const float4*)&smem[k * 128 + c0];
        float a = Hr[k];
        a0 += a * wv.x; a1 += a * wv.y; a2 += a * wv.z; a3 += a * wv.w;
      }
      float4 bv = *(const float4*)&b2[c0];
      float x0 = tanhf(a0 + bv.x), x1 = tanhf(a1 + bv.y);
      float x2 = tanhf(a2 + bv.z), x3 = tanhf(a3 + bv.w);
      const float* X0 = xbt + row * 132;
      *(float4*)&xs[(size_t)(r0 + row) * 128 + c0] =
          make_float4(X0[c0] + x0, X0[c0 + 1] + x1, X0[c0 + 2] + x2, X0[c0 + 3] + x3);
      recT[(c0 + 0) * 17 + row] = x0; recT[(c0 + 1) * 17 + row] = x1;
      recT[(c0 + 2) * 17 + row] = x2; recT[(c0 + 3) * 17 + row] = x3;
    }
  }
  __syncthreads();
  float* orc = out_rec + (size_t)b * 8192 + n0;
  for (int t = tid; t < 2048; t += 1024) {
    int w = t >> 4, i = t & 15;
    orc[w * 64 + i] = recT[w * 17 + i];
  }
}

// ================= K2: attn with LDS-GEMM L/R projection + fused rank-1 GAT dots (R19/R21) =================
__global__ __launch_bounds__(512) void k_attn(const float* __restrict__ xs, const float* __restrict__ ta_w,
                                              const float* __restrict__ ta_b, const float* __restrict__ ta_a,
                                              const float* __restrict__ ta_bias, const float* __restrict__ VAV,
                                              float* __restrict__ PART) {
  __shared__ float smem[38272];   // 153088 B
  float* Rf  = smem;
  float* XN  = smem + 16384;      // [64][136]
  float* WT  = smem + 25088;      // [128][65]
  float* Lh  = smem + 33408;
  float* av2 = smem + 37632;
  float* av6 = smem + 37760;
  float* tbs = smem + 37888;
  float* uu  = smem + 38016;
  float* vv  = smem + 38048;
  float* vva = smem + 38176;
  float* vvd = smem + 38208;
  float* vvf = smem + 38240;
  float* scratch = WT;

  int tid = threadIdx.x;
  int b = blockIdx.x >> 2, q = blockIdx.x & 3;
  int i0 = q * 32;

  {
    const float* xsb = xs + (size_t)b * 8192;
#pragma unroll
    for (int t = 0; t < 16; t++) {
      int idx = tid + t * 512;
      XN[(idx >> 7) * 136 + (idx & 127)] = xsb[idx];
    }
  }
#pragma unroll
  for (int t = 0; t < 16; t++) {
    int idx = tid + t * 512;
    int e = idx & 127, n = idx >> 7;
    WT[e * 65 + n] = ta_w[(64 + n) * 128 + e];
  }
  if (tid < 128) {
    float a = ta_a[tid];
    av2[tid] = 0.4f * a; av6[tid] = 0.6f * a;
    tbs[tid] = ta_b[tid];
  }
  if (tid >= 128 && tid < 160) {
    int i = tid - 128;
    vva[i] = VAV[i0 + i];
    vvd[i] = VAV[128 + i0 + i];
    vvf[i] = VAV[256 + i0 + i];
  }
  __syncthreads();

  {
    int et = tid >> 4, jt = tid & 15;
    int e0 = et * 4, j0 = jt * 8;
    float acc[4][8];
#pragma unroll
    for (int r = 0; r < 4; r++)
#pragma unroll
      for (int c = 0; c < 8; c++) acc[r][c] = 0.f;
#pragma unroll 4
    for (int n = 0; n < 64; n++) {
      float4 b0 = *(const float4*)&XN[n * 136 + j0];
      float4 b1 = *(const float4*)&XN[n * 136 + j0 + 4];
      float bb[8] = {b0.x, b0.y, b0.z, b0.w, b1.x, b1.y, b1.z, b1.w};
#pragma unroll
      for (int r = 0; r < 4; r++) {
        float a = WT[(e0 + r) * 65 + n];
#pragma unroll
        for (int c = 0; c < 8; c++) acc[r][c] += a * bb[c];
      }
    }
#pragma unroll
    for (int r = 0; r < 4; r++) {
      *(float4*)&Rf[(e0 + r) * 128 + j0] = make_float4(acc[r][0], acc[r][1], acc[r][2], acc[r][3]);
      *(float4*)&Rf[(e0 + r) * 128 + j0 + 4] = make_float4(acc[r][4], acc[r][5], acc[r][6], acc[r][7]);
    }
  }
  __syncthreads();
#pragma unroll
  for (int t = 0; t < 16; t++) {
    int idx = tid + t * 512;
    int e = idx & 127, n = idx >> 7;
    WT[e * 65 + n] = ta_w[n * 128 + e];
  }
  __syncthreads();

  {
    int e = tid >> 2, ig = tid & 3;
    int ii = ig * 8;
    float acc[8];
#pragma unroll
    for (int c = 0; c < 8; c++) acc[c] = 0.f;
#pragma unroll 4
    for (int n = 0; n < 64; n++) {
      float4 b0 = *(const float4*)&XN[n * 136 + i0 + ii];
      float4 b1 = *(const float4*)&XN[n * 136 + i0 + ii + 4];
      float a = WT[e * 65 + n];
      acc[0] += a * b0.x; acc[1] += a * b0.y; acc[2] += a * b0.z; acc[3] += a * b0.w;
      acc[4] += a * b1.x; acc[5] += a * b1.y; acc[6] += a * b1.z; acc[7] += a * b1.w;
    }
    float tb = tbs[e];
#pragma unroll
    for (int c = 0; c < 8; c++) Lh[e * 32 + ii + c] = acc[c] + tb;
  }
  __syncthreads();

  if (tid < 160) {
    float acc = 0.f;
    if (tid < 128) {
      for (int e = 0; e < 128; e++) acc += av6[e] * Rf[e * 128 + tid];
      vv[tid] = acc;
    } else {
      int i = tid - 128;
      for (int e = 0; e < 128; e++) acc += av6[e] * Lh[e * 32 + i];
      uu[i] = acc;
    }
  }
  __syncthreads();

  bool act = tid < 256;
  int tj = tid & 31, ti = (tid >> 5) & 7;
  float p[4][4];
  if (act) {
    float acc[4][4];
#pragma unroll
    for (int a = 0; a < 4; a++)
#pragma unroll
      for (int j = 0; j < 4; j++) acc[a][j] = 0.f;
#pragma unroll 2
    for (int e = 0; e < 128; e++) {
      float4 Lv = *(const float4*)&Lh[e * 32 + ti * 4];
      float4 Rv = *(const float4*)&Rf[e * 128 + tj * 4];
      float ae = av2[e];
      float La[4] = {Lv.x, Lv.y, Lv.z, Lv.w};
      float Ra[4] = {Rv.x, Rv.y, Rv.z, Rv.w};
#pragma unroll
      for (int a = 0; a < 4; a++)
#pragma unroll
        for (int j = 0; j < 4; j++) {
          float t = La[a] + Ra[j];
          acc[a][j] += ae * fabsf(t);
        }
    }
#pragma unroll
    for (int a = 0; a < 4; a++) {
      int i = i0 + ti * 4 + a;
      float uvi = uu[ti * 4 + a];
      float4 bv = *(const float4*)&ta_bias[(size_t)i * 128 + tj * 4];
      float v0 = acc[a][0] + bv.x + uvi + vv[tj * 4 + 0];
      float v1 = acc[a][1] + bv.y + uvi + vv[tj * 4 + 1];
      float v2 = acc[a][2] + bv.z + uvi + vv[tj * 4 + 2];
      float v3 = acc[a][3] + bv.w + uvi + vv[tj * 4 + 3];
      float m = fmaxf(fmaxf(v0, v1), fmaxf(v2, v3));
#pragma unroll
      for (int o = 16; o > 0; o >>= 1) m = fmaxf(m, __shfl_xor(m, o));
      float e0 = __expf(v0 - m), e1 = __expf(v1 - m), e2 = __expf(v2 - m), e3 = __expf(v3 - m);
      float s = e0 + e1 + e2 + e3;
#pragma unroll
      for (int o = 16; o > 0; o >>= 1) s += __shfl_xor(s, o);
      float inv = 1.f / s;
      p[a][0] = e0 * inv; p[a][1] = e1 * inv; p[a][2] = e2 * inv; p[a][3] = e3 * inv;
    }
  }
  __syncthreads();
  float* P = Lh;
  if (act) {
#pragma unroll
    for (int a = 0; a < 4; a++)
      *(float4*)&P[(ti * 4 + a) * 132 + tj * 4] = make_float4(p[a][0], p[a][1], p[a][2], p[a][3]);
  }
  __syncthreads();

  int tn = tid & 15, i2 = tid >> 4;
  float o0 = 0, o1 = 0, o2 = 0, o3 = 0;
  const float* Prow = P + i2 * 132;
  const float* X0 = XN + (tn +  0) * 136;
  const float* X1 = XN + (tn + 16) * 136;
  const float* X2 = XN + (tn + 32) * 136;
  const float* X3 = XN + (tn + 48) * 136;
#pragma unroll 4
  for (int j4 = 0; j4 < 32; j4++) {
    float4 pv = *(const float4*)&Prow[j4 * 4];
    float4 a0 = *(const float4*)&X0[j4 * 4];
    float4 a1 = *(const float4*)&X1[j4 * 4];
    float4 a2 = *(const float4*)&X2[j4 * 4];
    float4 a3 = *(const float4*)&X3[j4 * 4];
    o0 += pv.x * a0.x + pv.y * a0.y + pv.z * a0.z + pv.w * a0.w;
    o1 += pv.x * a1.x + pv.y * a1.y + pv.z * a1.z + pv.w * a1.w;
    o2 += pv.x * a2.x + pv.y * a2.y + pv.z * a2.z + pv.w * a2.w;
    o3 += pv.x * a3.x + pv.y * a3.y + pv.z * a3.z + pv.w * a3.w;
  }
  float t0 = tanhf(o0), t1 = tanhf(o1), t2 = tanhf(o2), t3 = tanhf(o3);
  {
    float wa = vva[i2], wd = vvd[i2], wf = vvf[i2];
    int base = i2 * 66 + tn;
    scratch[base +  0] = t0 * wa; scratch[base + 16] = t1 * wa;
    scratch[base + 32] = t2 * wa; scratch[base + 48] = t3 * wa;
    scratch[2112 + base +  0] = t0 * wd; scratch[2112 + base + 16] = t1 * wd;
    scratch[2112 + base + 32] = t2 * wd; scratch[2112 + base + 48] = t3 * wd;
    scratch[4224 + base +  0] = t0 * wf; scratch[4224 + base + 16] = t1 * wf;
    scratch[4224 + base + 32] = t2 * wf; scratch[4224 + base + 48] = t3 * wf;
  }
  __syncthreads();
  if (tid < 192) {
    int arr = tid >> 6, n = tid & 63;
    const float* sp = scratch + arr * 2112 + n;
    float s = 0.f;
#pragma unroll 8
    for (int i = 0; i < 32; i++) s += sp[i * 66];
    PART[(size_t)b * 768 + q * 192 + arr * 64 + n] = s;
  }
}

// ================= K3: final edge-softmax + FC (tiny) =================
__global__ __launch_bounds__(64) void k_fin(const float* __restrict__ PART, const float* __restrict__ VAV,
                                            const int* __restrict__ off, const int* __restrict__ list,
                                            const float* __restrict__ fcb, float* __restrict__ outp) {
  __shared__ float ss_s[64], sd_s[64], pf_s[64];
  int tid = threadIdx.x, b = blockIdx.x;
  const float* pb = PART + (size_t)b * 768;
  {
    float s0 = 0, s1 = 0, s2 = 0;
#pragma unroll
    for (int q2 = 0; q2 < 4; q2++) {
      const float* p = pb + q2 * 192;
      s0 += p[tid]; s1 += p[64 + tid]; s2 += p[128 + tid];
    }
    ss_s[tid] = s0; sd_s[tid] = s1; pf_s[tid] = s2;
  }
  __syncthreads();
  int e0 = off[tid], e1 = off[tid + 1];
  float sdv = sd_s[tid];
  float mx = -1e30f;
  for (int e = e0; e < e1; e++) {
    float t = ss_s[list[e]] + sdv;
    t = fmaxf(t, 0.2f * t);
    mx = fmaxf(mx, t);
  }
  float den = 0.f, acc = 0.f;
  for (int e = e0; e < e1; e++) {
    int s = list[e];
    float t = ss_s[s] + sdv;
    t = fmaxf(t, 0.2f * t);
    float w = __expf(t - mx);
    den += w;
    acc += w * pf_s[s];
  }
  outp[b * 64 + tid] = tanhf(acc / den + VAV[384] + fcb[0]);
}

extern "C" void kernel_launch(void* const* d_in, const int* in_sizes, int n_in,
                              void* d_out, int out_size, void* d_ws, size_t ws_size,
                              hipStream_t stream) {
  (void)n_in; (void)out_size; (void)ws_size;
  const float* x        = (const float*)d_in[0];
  const float* gl_embed = (const float*)d_in[7];
  const float* gcn_w    = (const float*)d_in[8];
  const float* gcn_b    = (const float*)d_in[9];
  const float* mlp_w1   = (const float*)d_in[10];
  const float* mlp_b1   = (const float*)d_in[11];
  const float* mlp_w2   = (const float*)d_in[12];
  const float* mlp_b2   = (const float*)d_in[13];
  const float* ta_w     = (const float*)d_in[14];
  const float* ta_b     = (const float*)d_in[15];
  const float* ta_a     = (const float*)d_in[16];
  const float* ta_bias  = (const float*)d_in[17];
  const float* gat_w    = (const float*)d_in[18];
  const float* gat_asrc = (const float*)d_in[19];
  const float* gat_adst = (const float*)d_in[20];
  const float* gat_b    = (const float*)d_in[21];
  const float* fc_w     = (const float*)d_in[22];
  const float* fc_b     = (const float*)d_in[23];
  const int*   gat_ei   = (const int*)d_in[24];
  const int*   gl_ei    = (const int*)d_in[25];

  int E_gat = in_sizes[24] / (2 * BB);  // 1280
  int E_gl  = in_sizes[25] / (2 * BB);  // 1638

  float* ws = (float*)d_ws;
  float* XS    = ws + 0;        // 524288
  int*   IP    = (int*)(ws + 524288);
  int* GATOFF  = IP;            // 72
  int* GATLIST = IP + 72;       // 2048
  float* VAV   = ws + 526848;   // 512
  float* PART  = ws + 527360;   // 49152

  float* out_rec = (float*)d_out;
  float* out_pre = (float*)d_out + 524288;

  k_front<<<260, 1024, 0, stream>>>(x, gl_embed, gcn_w, gcn_b, mlp_w1, mlp_b1, mlp_w2, mlp_b2,
                                    gl_ei, E_gl, gat_ei, E_gat,
                                    gat_w, gat_asrc, gat_adst, fc_w, gat_b,
                                    XS, out_rec, VAV, GATOFF, GATLIST);
  k_attn<<<256, 512, 0, stream>>>(XS, ta_w, ta_b, ta_a, ta_bias, VAV, PART);
  k_fin<<<64, 64, 0, stream>>>(PART, VAV, GATOFF, GATLIST, fc_b, out_pre);
}